// Round 2
// baseline (272.798 us; speedup 1.0000x reference)
//
#include <hip/hip_runtime.h>

#define N_NODES 50000
#define N_EDGES 800000
#define NBUCK 196    // dst>>8 -> 0..195
#define NHIST 196    // histogram blocks (4096 edges each)

typedef __attribute__((ext_vector_type(8))) short short8;
typedef __attribute__((ext_vector_type(4))) float f32x4;
typedef __attribute__((ext_vector_type(4))) unsigned short ushort4v;
typedef __attribute__((ext_vector_type(8))) unsigned short ushort8v;

// ---------------- split-bf16 helpers ----------------
// f32 = hi(bf16) + lo(bf16) + O(2^-33). Self path uses Ahi*Bhi+Ahi*Blo+Alo*Bhi;
// agg path (already bf16-rounded gather) uses Ahi*Bhi+Ahi*Blo only.

__device__ inline void split_bf16(float f, unsigned short& hi, unsigned short& lo) {
    union { float f; unsigned u; } a; a.f = f;
    unsigned r = (a.u + 0x7fffu + ((a.u >> 16) & 1u)) >> 16;  // RNE to bf16
    hi = (unsigned short)r;
    union { unsigned u; float f; } b; b.u = r << 16;
    union { float f; unsigned u; } c; c.f = f - b.f;
    unsigned r2 = (c.u + 0x7fffu + ((c.u >> 16) & 1u)) >> 16;
    lo = (unsigned short)r2;
}

__device__ inline unsigned short f2bf(float f) {
    union { float f; unsigned u; } a; a.f = f;
    return (unsigned short)((a.u + 0x7fffu + ((a.u >> 16) & 1u)) >> 16);
}

__device__ inline float bf2f(unsigned short u) {
    union { unsigned u; float f; } a; a.u = (unsigned)u << 16; return a.f;
}

// ---------------- prep: pack(W) + split(x) + bucket histogram ----------------

__global__ void prep_kernel(const float* __restrict__ W0, const float* __restrict__ W1,
                            const float* __restrict__ W2, const float* __restrict__ W3,
                            const float* __restrict__ W4, const float* __restrict__ W5,
                            unsigned short* __restrict__ wout,
                            const float* __restrict__ x, unsigned short* __restrict__ xhi,
                            unsigned short* __restrict__ xlo,
                            const int* __restrict__ dst, int* __restrict__ blkhist) {
    __shared__ int lhist[NBUCK];
    if (blockIdx.x < 320) {
        int t = blockIdx.x * 256 + threadIdx.x;  // 0..81919
        const float* W; int D, local, half; size_t base;
        if (t < 65536) {
            int mat = t >> 14; local = t & 16383; D = 128; half = 16384;
            base = (size_t)mat * 32768;
            W = mat == 0 ? W0 : mat == 1 ? W1 : mat == 2 ? W2 : W3;
        } else {
            int m = (t - 65536) >> 13; local = (t - 65536) & 8191; D = 64; half = 8192;
            base = 131072 + (size_t)m * 16384;
            W = m == 0 ? W4 : W5;
        }
        int j = local & 7, lane = (local >> 3) & 63, ks = (local >> 9) & 3, ct = local >> 11;
        int k = ks * 32 + ((lane >> 4) << 3) + j;
        int n = (ct << 4) + (lane & 15);
        unsigned short hi, lo;
        split_bf16(W[k * D + n], hi, lo);
        wout[base + local] = hi;
        wout[base + half + local] = lo;
    } else if (blockIdx.x < 1883) {
        int t = (blockIdx.x - 320) * 256 + threadIdx.x;  // one 16-float chunk/thread
        if (t >= N_NODES * 8) return;                    // 50000*128/16 = 400000
        const float* p = x + (size_t)t * 16;
#pragma unroll
        for (int half = 0; half < 2; ++half) {
            float4 v0 = *(const float4*)(p + half * 8);
            float4 v1 = *(const float4*)(p + half * 8 + 4);
            float vv[8] = {v0.x, v0.y, v0.z, v0.w, v1.x, v1.y, v1.z, v1.w};
            ushort8v h, l;
#pragma unroll
            for (int j = 0; j < 8; ++j) {
                unsigned short a, b;
                split_bf16(vv[j], a, b);
                h[j] = a; l[j] = b;
            }
            *(ushort8v*)(xhi + (size_t)t * 16 + half * 8) = h;
            *(ushort8v*)(xlo + (size_t)t * 16 + half * 8) = l;
        }
    } else {
        const int hb = blockIdx.x - 1883;
        const int base = hb * 4096;
        if (threadIdx.x < NBUCK) lhist[threadIdx.x] = 0;
        __syncthreads();
#pragma unroll
        for (int i = 0; i < 16; ++i) {
            int e = base + i * 256 + threadIdx.x;
            if (e < N_EDGES) atomicAdd(&lhist[dst[e] >> 8], 1);
        }
        __syncthreads();
        if (threadIdx.x < NBUCK) blkhist[hb * NBUCK + threadIdx.x] = lhist[threadIdx.x];
    }
}

// ---------------- bucket scan (1 block): blkhist -> bucketBase/bucketCur -----

__global__ void scan_sums_kernel(const int* __restrict__ blkhist,
                                 int* __restrict__ bucketBase, int* __restrict__ bucketCur,
                                 int* __restrict__ rowptr) {
    __shared__ int s[256];
    int tid = threadIdx.x;
    int v = 0;
    if (tid < NBUCK)
        for (int h = 0; h < NHIST; ++h) v += blkhist[h * NBUCK + tid];
    s[tid] = v;
    __syncthreads();
    for (int off = 1; off < 256; off <<= 1) {
        int t = (tid >= off) ? s[tid - off] : 0;
        __syncthreads();
        s[tid] += t;
        __syncthreads();
    }
    if (tid < NBUCK) {
        int b = s[tid] - v;
        bucketBase[tid] = b;
        bucketCur[tid] = b;
    }
    if (tid == 0) { bucketBase[NBUCK] = N_EDGES; rowptr[N_NODES] = N_EDGES; }
}

// ---------------- edge partition into 196 buckets (LDS-staged, coalesced) ----

__global__ __launch_bounds__(256) void partition_kernel(
    const int* __restrict__ src, const int* __restrict__ dst,
    int* __restrict__ bucketCur, unsigned int* __restrict__ ebuf, int E) {
    __shared__ int hist[NBUCK], binoff[NBUCK], bincur[NBUCK], runstart[NBUCK];
    __shared__ int scanbuf[256];
    __shared__ unsigned int sortbuf[2048];
    const int tid = threadIdx.x;
    const int base = blockIdx.x * 2048;
    if (tid < NBUCK) hist[tid] = 0;
    __syncthreads();
    int myb[8]; unsigned int myp[8];
#pragma unroll
    for (int i = 0; i < 8; ++i) {
        int e = base + i * 256 + tid;
        if (e < E) {
            int d = dst[e], s = src[e];
            myb[i] = d >> 8;
            myp[i] = ((unsigned)d << 16) | (unsigned)s;
            atomicAdd(&hist[myb[i]], 1);
        } else myb[i] = -1;
    }
    __syncthreads();
    int v = (tid < NBUCK) ? hist[tid] : 0;
    scanbuf[tid] = v;
    __syncthreads();
    for (int off = 1; off < 256; off <<= 1) {
        int t = (tid >= off) ? scanbuf[tid - off] : 0;
        __syncthreads();
        scanbuf[tid] += t;
        __syncthreads();
    }
    if (tid < NBUCK) {
        binoff[tid] = scanbuf[tid] - v;
        bincur[tid] = 0;
        runstart[tid] = atomicAdd(&bucketCur[tid], v);
    }
    __syncthreads();
#pragma unroll
    for (int i = 0; i < 8; ++i) {
        if (myb[i] >= 0) {
            int r = atomicAdd(&bincur[myb[i]], 1);
            sortbuf[binoff[myb[i]] + r] = myp[i];
        }
    }
    __syncthreads();
    int nloc = E - base; if (nloc > 2048) nloc = 2048;
#pragma unroll
    for (int i = 0; i < 8; ++i) {
        int idx = i * 256 + tid;
        if (idx < nloc) {
            unsigned int p = sortbuf[idx];
            int b = p >> 24;   // dst>>8
            ebuf[runstart[b] + (idx - binoff[b])] = p;
        }
    }
}

// ---------------- fine fill: per bucket, derive rowptr + scatter esrc ---------

__global__ __launch_bounds__(256) void fine_fill_kernel(
    const unsigned int* __restrict__ ebuf, const int* __restrict__ bucketBase,
    int* __restrict__ rowptr, unsigned short* __restrict__ esrc, int n) {
    __shared__ int cnt[256], scanbuf[256], cur[256];
    const int b = blockIdx.x, tid = threadIdx.x;
    const int nbase = b << 8;
    cnt[tid] = 0;
    __syncthreads();
    const int lo = bucketBase[b], hi = bucketBase[b + 1];
    for (int k = lo + tid; k < hi; k += 256)
        atomicAdd(&cnt[(ebuf[k] >> 16) & 255], 1);
    __syncthreads();
    int v = cnt[tid];
    scanbuf[tid] = v;
    __syncthreads();
    for (int off = 1; off < 256; off <<= 1) {
        int t = (tid >= off) ? scanbuf[tid - off] : 0;
        __syncthreads();
        scanbuf[tid] += t;
        __syncthreads();
    }
    int start = lo + scanbuf[tid] - v;   // exclusive
    if (nbase + tid < n) rowptr[nbase + tid] = start;
    cur[tid] = start;
    __syncthreads();
    for (int k = lo + tid; k < hi; k += 256) {
        unsigned int p = ebuf[k];
        int pos = atomicAdd(&cur[(p >> 16) & 255], 1);
        esrc[pos] = (unsigned short)(p & 0xFFFFu);
    }
}

// ---------------- fused SAGE layer: gather-mean (in-block) + dual MFMA GEMM --
// Phase A: stage this block's 32 self rows (hi+lo planes) into LDS.
// Phase B: mean-aggregate neighbors of the same 32 rows directly into As[0].
//   Each 16-lane group owns 2 rows and walks both neighbor lists in ONE fused
//   loop -> 8 gather loads in flight (R1: was 4, latency-bound at occ 40%).
//   2 accumulator sets of 8 f32 (16 VGPR) keep total VGPR < 64 so 6 blocks/CU
//   are resident (launch_bounds(256,6); LDS 26112*6 = 153KB fits 160KB).
// Phase C: dual GEMM out = agg@W1 + self@W2 + b. agg: 2 MFMAs (hi*bhi+hi*blo);
//   self: 3 MFMAs (hi*bhi+hi*blo+lo*bhi). BM=32, 256 thr = 4 waves.
// NOT in-place: reads Hhi/Hlo, writes out planes (ping-pong buffers).

template <int DOUT, bool RELU, bool SPLIT_OUT>
__global__ __launch_bounds__(256, 6) void sage_layer(
    const unsigned short* __restrict__ Hhi, const unsigned short* __restrict__ Hlo,
    const int* __restrict__ rowptr, const unsigned short* __restrict__ esrc,
    const unsigned short* __restrict__ B1p, const unsigned short* __restrict__ B2p,
    const float* __restrict__ bias, float* __restrict__ outf,
    unsigned short* __restrict__ outhi, unsigned short* __restrict__ outlo, int M) {
    constexpr int K = 128, BM = 32, KS = 4, CT = DOUT / 16, CPW = CT / 4;
    constexpr int PITCH = K + 8;
    constexpr int HALF = CT * KS * 512;
    __shared__ unsigned short As[3][BM * PITCH];  // [agg-hi, self-hi, self-lo]

    const int tid = threadIdx.x;
    const int r0 = blockIdx.x * BM;

    // ---- Phase A: stage self hi/lo rows (coalesced, 2 chunks/thread/plane) ----
    const unsigned short* __restrict__ srcs[2] = {Hhi, Hlo};
#pragma unroll
    for (int s = 0; s < 2; ++s) {
#pragma unroll
        for (int c = 0; c < 2; ++c) {
            int chunk = tid + c * 256;
            int row = chunk >> 4;
            int c8 = (chunk & 15) * 8;
            int grow = r0 + row; if (grow >= M) grow = M - 1;
            *(ushort8v*)(&As[s + 1][row * PITCH + c8]) =
                *(const ushort8v*)(srcs[s] + (size_t)grow * K + c8);
        }
    }

    // ---- Phase B: fused mean-aggregate into As[0], dual-row interleaved ----
    {
        const int g16 = tid >> 4, l16 = tid & 15;
        const int rowA = g16 * 2, rowB = rowA + 1;
        int nodeA = r0 + rowA; if (nodeA >= M) nodeA = M - 1;  // pad: harmless dup
        int nodeB = r0 + rowB; if (nodeB >= M) nodeB = M - 1;
        const int begA = rowptr[nodeA], endA = rowptr[nodeA + 1];
        const int begB = rowptr[nodeB], endB = rowptr[nodeB + 1];
        const unsigned short* __restrict__ Hb = Hhi + l16 * 8;
        float accA[8] = {0,0,0,0,0,0,0,0}, accB[8] = {0,0,0,0,0,0,0,0};
        int kA = begA, kB = begB;
        // fused main loop: 8 gather loads in flight across two independent rows
        for (; kA + 4 <= endA && kB + 4 <= endB; kA += 4, kB += 4) {
            int eA0 = esrc[kA], eA1 = esrc[kA + 1], eA2 = esrc[kA + 2], eA3 = esrc[kA + 3];
            int eB0 = esrc[kB], eB1 = esrc[kB + 1], eB2 = esrc[kB + 2], eB3 = esrc[kB + 3];
            ushort8v vA0 = *(const ushort8v*)(Hb + (size_t)eA0 * 128);
            ushort8v vA1 = *(const ushort8v*)(Hb + (size_t)eA1 * 128);
            ushort8v vA2 = *(const ushort8v*)(Hb + (size_t)eA2 * 128);
            ushort8v vA3 = *(const ushort8v*)(Hb + (size_t)eA3 * 128);
            ushort8v vB0 = *(const ushort8v*)(Hb + (size_t)eB0 * 128);
            ushort8v vB1 = *(const ushort8v*)(Hb + (size_t)eB1 * 128);
            ushort8v vB2 = *(const ushort8v*)(Hb + (size_t)eB2 * 128);
            ushort8v vB3 = *(const ushort8v*)(Hb + (size_t)eB3 * 128);
#pragma unroll
            for (int j = 0; j < 8; ++j) {
                accA[j] += bf2f(vA0[j]); accA[j] += bf2f(vA1[j]);
                accA[j] += bf2f(vA2[j]); accA[j] += bf2f(vA3[j]);
                accB[j] += bf2f(vB0[j]); accB[j] += bf2f(vB1[j]);
                accB[j] += bf2f(vB2[j]); accB[j] += bf2f(vB3[j]);
            }
        }
        // drain A: 4-way then scalar
        for (; kA + 4 <= endA; kA += 4) {
            int e0 = esrc[kA], e1 = esrc[kA + 1], e2 = esrc[kA + 2], e3 = esrc[kA + 3];
            ushort8v v0 = *(const ushort8v*)(Hb + (size_t)e0 * 128);
            ushort8v v1 = *(const ushort8v*)(Hb + (size_t)e1 * 128);
            ushort8v v2 = *(const ushort8v*)(Hb + (size_t)e2 * 128);
            ushort8v v3 = *(const ushort8v*)(Hb + (size_t)e3 * 128);
#pragma unroll
            for (int j = 0; j < 8; ++j) {
                accA[j] += bf2f(v0[j]); accA[j] += bf2f(v1[j]);
                accA[j] += bf2f(v2[j]); accA[j] += bf2f(v3[j]);
            }
        }
        for (; kA < endA; ++kA) {
            int e0 = esrc[kA];
            ushort8v v0 = *(const ushort8v*)(Hb + (size_t)e0 * 128);
#pragma unroll
            for (int j = 0; j < 8; ++j) accA[j] += bf2f(v0[j]);
        }
        // drain B: 4-way then scalar
        for (; kB + 4 <= endB; kB += 4) {
            int e0 = esrc[kB], e1 = esrc[kB + 1], e2 = esrc[kB + 2], e3 = esrc[kB + 3];
            ushort8v v0 = *(const ushort8v*)(Hb + (size_t)e0 * 128);
            ushort8v v1 = *(const ushort8v*)(Hb + (size_t)e1 * 128);
            ushort8v v2 = *(const ushort8v*)(Hb + (size_t)e2 * 128);
            ushort8v v3 = *(const ushort8v*)(Hb + (size_t)e3 * 128);
#pragma unroll
            for (int j = 0; j < 8; ++j) {
                accB[j] += bf2f(v0[j]); accB[j] += bf2f(v1[j]);
                accB[j] += bf2f(v2[j]); accB[j] += bf2f(v3[j]);
            }
        }
        for (; kB < endB; ++kB) {
            int e0 = esrc[kB];
            ushort8v v0 = *(const ushort8v*)(Hb + (size_t)e0 * 128);
#pragma unroll
            for (int j = 0; j < 8; ++j) accB[j] += bf2f(v0[j]);
        }
        float invA = (endA > begA) ? 1.0f / (float)(endA - begA) : 0.0f;
        float invB = (endB > begB) ? 1.0f / (float)(endB - begB) : 0.0f;
        ushort8v mA, mB;
#pragma unroll
        for (int j = 0; j < 8; ++j) {
            mA[j] = f2bf(accA[j] * invA);
            mB[j] = f2bf(accB[j] * invB);
        }
        *(ushort8v*)(&As[0][rowA * PITCH + l16 * 8]) = mA;
        *(ushort8v*)(&As[0][rowB * PITCH + l16 * 8]) = mB;
    }
    __syncthreads();

    // ---- Phase C: dual GEMM via MFMA ----
    const int wave = tid >> 6, lane = tid & 63;
    const int rl = lane & 15, quad = lane >> 4;

    f32x4 acc[2][CPW];
#pragma unroll
    for (int c = 0; c < CPW; ++c) {
        float bv = bias[(wave * CPW + c) * 16 + rl];
        acc[0][c] = (f32x4){bv, bv, bv, bv};
        acc[1][c] = acc[0][c];
    }

#pragma unroll
    for (int ks = 0; ks < KS; ++ks) {
        short8 a_ag[2], a_sh[2][2];
#pragma unroll
        for (int rt = 0; rt < 2; ++rt) {
            int off = (rt * 16 + rl) * PITCH + ks * 32 + quad * 8;
            a_ag[rt]    = *(const short8*)(&As[0][off]);
            a_sh[rt][0] = *(const short8*)(&As[1][off]);
            a_sh[rt][1] = *(const short8*)(&As[2][off]);
        }
        short8 b1[CPW][2], b2[CPW][2];
#pragma unroll
        for (int c = 0; c < CPW; ++c) {
            size_t boff = (((wave * CPW + c) * KS + ks) * 64 + lane) * 8;
#pragma unroll
            for (int p = 0; p < 2; ++p) {
                b1[c][p] = *(const short8*)(B1p + p * HALF + boff);
                b2[c][p] = *(const short8*)(B2p + p * HALF + boff);
            }
        }
#pragma unroll
        for (int rt = 0; rt < 2; ++rt)
#pragma unroll
            for (int c = 0; c < CPW; ++c) {
                acc[rt][c] = __builtin_amdgcn_mfma_f32_16x16x32_bf16(a_ag[rt],    b1[c][0], acc[rt][c], 0, 0, 0);
                acc[rt][c] = __builtin_amdgcn_mfma_f32_16x16x32_bf16(a_ag[rt],    b1[c][1], acc[rt][c], 0, 0, 0);
                acc[rt][c] = __builtin_amdgcn_mfma_f32_16x16x32_bf16(a_sh[rt][0], b2[c][0], acc[rt][c], 0, 0, 0);
                acc[rt][c] = __builtin_amdgcn_mfma_f32_16x16x32_bf16(a_sh[rt][0], b2[c][1], acc[rt][c], 0, 0, 0);
                acc[rt][c] = __builtin_amdgcn_mfma_f32_16x16x32_bf16(a_sh[rt][1], b2[c][0], acc[rt][c], 0, 0, 0);
            }
    }

    // ---- epilogue: C/D layout col=lane&15, row=quad*4+reg ----
#pragma unroll
    for (int rt = 0; rt < 2; ++rt)
#pragma unroll
        for (int c = 0; c < CPW; ++c) {
            int col = (wave * CPW + c) * 16 + rl;
            int rowb = r0 + rt * 16 + quad * 4;
#pragma unroll
            for (int r = 0; r < 4; ++r) {
                int rr = rowb + r;
                if (rr < M) {
                    float vv = acc[rt][c][r];
                    if (RELU) vv = fmaxf(vv, 0.f);
                    if (SPLIT_OUT) {
                        unsigned short h, l;
                        split_bf16(vv, h, l);
                        outhi[(size_t)rr * DOUT + col] = h;
                        outlo[(size_t)rr * DOUT + col] = l;
                    } else {
                        outf[(size_t)rr * DOUT + col] = vv;
                    }
                }
            }
        }
}

// ---------------- launch ----------------

extern "C" void kernel_launch(void* const* d_in, const int* in_sizes, int n_in,
                              void* d_out, int out_size, void* d_ws, size_t ws_size,
                              hipStream_t stream) {
    const float* x   = (const float*)d_in[0];
    const int* eidx  = (const int*)d_in[1];
    const int* src   = eidx;             // edge_index[0]
    const int* dst   = eidx + N_EDGES;   // edge_index[1]
    const float* Wl0 = (const float*)d_in[2];
    const float* b0  = (const float*)d_in[3];
    const float* Wr0 = (const float*)d_in[4];
    const float* Wl1 = (const float*)d_in[5];
    const float* b1  = (const float*)d_in[6];
    const float* Wr1 = (const float*)d_in[7];
    const float* Wl2 = (const float*)d_in[8];
    const float* b2  = (const float*)d_in[9];
    const float* Wr2 = (const float*)d_in[10];
    float* outp = (float*)d_out;

    // workspace (~54 MB): x planes + ping-pong h planes + CSR scratch
    unsigned short* xhi  = (unsigned short*)d_ws;             // N*128 each
    unsigned short* xlo  = xhi + (size_t)N_NODES * 128;
    unsigned short* h1hi = xlo + (size_t)N_NODES * 128;
    unsigned short* h1lo = h1hi + (size_t)N_NODES * 128;
    unsigned int* ebuf = (unsigned int*)h1hi;                 // ALIAS: consumed by
                                                              // fine_fill before layer0 writes h1
    int* rowptr    = (int*)(h1lo + (size_t)N_NODES * 128);    // 50016
    int* blkhist   = rowptr + 50016;                          // 196*196 = 38416
    int* bucketBase= blkhist + 38416;                         // 256 (197 used)
    int* bucketCur = bucketBase + 256;                        // 256
    unsigned short* esrc  = (unsigned short*)(bucketCur + 256); // E ushort = 1.6MB
    unsigned short* packw = esrc + N_EDGES;                   // 163840 bf16 (16B-aligned)
    unsigned short* Wl0p = packw;
    unsigned short* Wr0p = packw + 32768;
    unsigned short* Wl1p = packw + 65536;
    unsigned short* Wr1p = packw + 98304;
    unsigned short* Wl2p = packw + 131072;
    unsigned short* Wr2p = packw + 147456;

    // --- prep (pack W + split x + per-block bucket hist; no atomics to global) ---
    prep_kernel<<<2079, 256, 0, stream>>>(Wl0, Wr0, Wl1, Wr1, Wl2, Wr2, packw,
                                          x, xhi, xlo, dst, blkhist);
    // --- bucket scan (1 block) -> bucketBase/bucketCur, rowptr[N]=E ---
    scan_sums_kernel<<<1, 256, 0, stream>>>(blkhist, bucketBase, bucketCur, rowptr);
    // --- partition edges into buckets (coalesced), then per-bucket CSR ---
    partition_kernel<<<(N_EDGES + 2047) / 2048, 256, 0, stream>>>(src, dst, bucketCur, ebuf, N_EDGES);
    fine_fill_kernel<<<NBUCK, 256, 0, stream>>>(ebuf, bucketBase, rowptr, esrc, N_NODES);

    const int gemmGrid = (N_NODES + 31) / 32;   // 1563

    // layer 0: x -> h1 (ReLU, split planes)
    sage_layer<128, true, true><<<gemmGrid, 256, 0, stream>>>(
        xhi, xlo, rowptr, esrc, Wl0p, Wr0p, b0, nullptr, h1hi, h1lo, N_NODES);
    // layer 1: h1 -> x planes (ReLU, split planes; x planes dead after layer 0)
    sage_layer<128, true, true><<<gemmGrid, 256, 0, stream>>>(
        h1hi, h1lo, rowptr, esrc, Wl1p, Wr1p, b1, nullptr, xhi, xlo, N_NODES);
    // layer 2: x planes -> out (f32, no ReLU, DOUT=64)
    sage_layer<64, false, false><<<gemmGrid, 256, 0, stream>>>(
        xhi, xlo, rowptr, esrc, Wl2p, Wr2p, b2, outp, nullptr, nullptr, N_NODES);
}

// Round 5
// 270.546 us; speedup vs baseline: 1.0083x; 1.0083x over previous
//
#include <hip/hip_runtime.h>

#define N_NODES 50000
#define N_EDGES 800000
#define NBUCK 196    // dst>>8 -> 0..195
#define NHIST 196    // histogram blocks (4096 edges each)

typedef __attribute__((ext_vector_type(8))) short short8;
typedef __attribute__((ext_vector_type(4))) float f32x4;
typedef __attribute__((ext_vector_type(4))) unsigned short ushort4v;
typedef __attribute__((ext_vector_type(8))) unsigned short ushort8v;

// ---------------- split-bf16 helpers ----------------
// f32 = hi(bf16) + lo(bf16) + O(2^-33). Self path uses Ahi*Bhi+Ahi*Blo+Alo*Bhi;
// agg path (already bf16-rounded gather) uses Ahi*Bhi+Ahi*Blo only.

__device__ inline void split_bf16(float f, unsigned short& hi, unsigned short& lo) {
    union { float f; unsigned u; } a; a.f = f;
    unsigned r = (a.u + 0x7fffu + ((a.u >> 16) & 1u)) >> 16;  // RNE to bf16
    hi = (unsigned short)r;
    union { unsigned u; float f; } b; b.u = r << 16;
    union { float f; unsigned u; } c; c.f = f - b.f;
    unsigned r2 = (c.u + 0x7fffu + ((c.u >> 16) & 1u)) >> 16;
    lo = (unsigned short)r2;
}

__device__ inline unsigned short f2bf(float f) {
    union { float f; unsigned u; } a; a.f = f;
    return (unsigned short)((a.u + 0x7fffu + ((a.u >> 16) & 1u)) >> 16);
}

__device__ inline float bf2f(unsigned short u) {
    union { unsigned u; float f; } a; a.u = (unsigned)u << 16; return a.f;
}

// ---------------- prep: pack(W) + split(x) + bucket histogram ----------------

__global__ void prep_kernel(const float* __restrict__ W0, const float* __restrict__ W1,
                            const float* __restrict__ W2, const float* __restrict__ W3,
                            const float* __restrict__ W4, const float* __restrict__ W5,
                            unsigned short* __restrict__ wout,
                            const float* __restrict__ x, unsigned short* __restrict__ xhi,
                            unsigned short* __restrict__ xlo,
                            const int* __restrict__ dst, int* __restrict__ blkhist) {
    __shared__ int lhist[NBUCK];
    if (blockIdx.x < 320) {
        int t = blockIdx.x * 256 + threadIdx.x;  // 0..81919
        const float* W; int D, local, half; size_t base;
        if (t < 65536) {
            int mat = t >> 14; local = t & 16383; D = 128; half = 16384;
            base = (size_t)mat * 32768;
            W = mat == 0 ? W0 : mat == 1 ? W1 : mat == 2 ? W2 : W3;
        } else {
            int m = (t - 65536) >> 13; local = (t - 65536) & 8191; D = 64; half = 8192;
            base = 131072 + (size_t)m * 16384;
            W = m == 0 ? W4 : W5;
        }
        int j = local & 7, lane = (local >> 3) & 63, ks = (local >> 9) & 3, ct = local >> 11;
        int k = ks * 32 + ((lane >> 4) << 3) + j;
        int n = (ct << 4) + (lane & 15);
        unsigned short hi, lo;
        split_bf16(W[k * D + n], hi, lo);
        wout[base + local] = hi;
        wout[base + half + local] = lo;
    } else if (blockIdx.x < 1883) {
        int t = (blockIdx.x - 320) * 256 + threadIdx.x;  // one 16-float chunk/thread
        if (t >= N_NODES * 8) return;                    // 50000*128/16 = 400000
        const float* p = x + (size_t)t * 16;
#pragma unroll
        for (int half = 0; half < 2; ++half) {
            float4 v0 = *(const float4*)(p + half * 8);
            float4 v1 = *(const float4*)(p + half * 8 + 4);
            float vv[8] = {v0.x, v0.y, v0.z, v0.w, v1.x, v1.y, v1.z, v1.w};
            ushort8v h, l;
#pragma unroll
            for (int j = 0; j < 8; ++j) {
                unsigned short a, b;
                split_bf16(vv[j], a, b);
                h[j] = a; l[j] = b;
            }
            *(ushort8v*)(xhi + (size_t)t * 16 + half * 8) = h;
            *(ushort8v*)(xlo + (size_t)t * 16 + half * 8) = l;
        }
    } else {
        const int hb = blockIdx.x - 1883;
        const int base = hb * 4096;
        if (threadIdx.x < NBUCK) lhist[threadIdx.x] = 0;
        __syncthreads();
#pragma unroll
        for (int i = 0; i < 16; ++i) {
            int e = base + i * 256 + threadIdx.x;
            if (e < N_EDGES) atomicAdd(&lhist[dst[e] >> 8], 1);
        }
        __syncthreads();
        if (threadIdx.x < NBUCK) blkhist[hb * NBUCK + threadIdx.x] = lhist[threadIdx.x];
    }
}

// ---------------- bucket scan (1 block): blkhist -> bucketBase/bucketCur -----

__global__ void scan_sums_kernel(const int* __restrict__ blkhist,
                                 int* __restrict__ bucketBase, int* __restrict__ bucketCur,
                                 int* __restrict__ rowptr) {
    __shared__ int s[256];
    int tid = threadIdx.x;
    int v = 0;
    if (tid < NBUCK)
        for (int h = 0; h < NHIST; ++h) v += blkhist[h * NBUCK + tid];
    s[tid] = v;
    __syncthreads();
    for (int off = 1; off < 256; off <<= 1) {
        int t = (tid >= off) ? s[tid - off] : 0;
        __syncthreads();
        s[tid] += t;
        __syncthreads();
    }
    if (tid < NBUCK) {
        int b = s[tid] - v;
        bucketBase[tid] = b;
        bucketCur[tid] = b;
    }
    if (tid == 0) { bucketBase[NBUCK] = N_EDGES; rowptr[N_NODES] = N_EDGES; }
}

// ---------------- edge partition into 196 buckets (LDS-staged, coalesced) ----

__global__ __launch_bounds__(256) void partition_kernel(
    const int* __restrict__ src, const int* __restrict__ dst,
    int* __restrict__ bucketCur, unsigned int* __restrict__ ebuf, int E) {
    __shared__ int hist[NBUCK], binoff[NBUCK], bincur[NBUCK], runstart[NBUCK];
    __shared__ int scanbuf[256];
    __shared__ unsigned int sortbuf[2048];
    const int tid = threadIdx.x;
    const int base = blockIdx.x * 2048;
    if (tid < NBUCK) hist[tid] = 0;
    __syncthreads();
    int myb[8]; unsigned int myp[8];
#pragma unroll
    for (int i = 0; i < 8; ++i) {
        int e = base + i * 256 + tid;
        if (e < E) {
            int d = dst[e], s = src[e];
            myb[i] = d >> 8;
            myp[i] = ((unsigned)d << 16) | (unsigned)s;
            atomicAdd(&hist[myb[i]], 1);
        } else myb[i] = -1;
    }
    __syncthreads();
    int v = (tid < NBUCK) ? hist[tid] : 0;
    scanbuf[tid] = v;
    __syncthreads();
    for (int off = 1; off < 256; off <<= 1) {
        int t = (tid >= off) ? scanbuf[tid - off] : 0;
        __syncthreads();
        scanbuf[tid] += t;
        __syncthreads();
    }
    if (tid < NBUCK) {
        binoff[tid] = scanbuf[tid] - v;
        bincur[tid] = 0;
        runstart[tid] = atomicAdd(&bucketCur[tid], v);
    }
    __syncthreads();
#pragma unroll
    for (int i = 0; i < 8; ++i) {
        if (myb[i] >= 0) {
            int r = atomicAdd(&bincur[myb[i]], 1);
            sortbuf[binoff[myb[i]] + r] = myp[i];
        }
    }
    __syncthreads();
    int nloc = E - base; if (nloc > 2048) nloc = 2048;
#pragma unroll
    for (int i = 0; i < 8; ++i) {
        int idx = i * 256 + tid;
        if (idx < nloc) {
            unsigned int p = sortbuf[idx];
            int b = p >> 24;   // dst>>8
            ebuf[runstart[b] + (idx - binoff[b])] = p;
        }
    }
}

// ---------------- fine fill: per bucket, derive rowptr + scatter esrc ---------

__global__ __launch_bounds__(256) void fine_fill_kernel(
    const unsigned int* __restrict__ ebuf, const int* __restrict__ bucketBase,
    int* __restrict__ rowptr, unsigned short* __restrict__ esrc, int n) {
    __shared__ int cnt[256], scanbuf[256], cur[256];
    const int b = blockIdx.x, tid = threadIdx.x;
    const int nbase = b << 8;
    cnt[tid] = 0;
    __syncthreads();
    const int lo = bucketBase[b], hi = bucketBase[b + 1];
    for (int k = lo + tid; k < hi; k += 256)
        atomicAdd(&cnt[(ebuf[k] >> 16) & 255], 1);
    __syncthreads();
    int v = cnt[tid];
    scanbuf[tid] = v;
    __syncthreads();
    for (int off = 1; off < 256; off <<= 1) {
        int t = (tid >= off) ? scanbuf[tid - off] : 0;
        __syncthreads();
        scanbuf[tid] += t;
        __syncthreads();
    }
    int start = lo + scanbuf[tid] - v;   // exclusive
    if (nbase + tid < n) rowptr[nbase + tid] = start;
    cur[tid] = start;
    __syncthreads();
    for (int k = lo + tid; k < hi; k += 256) {
        unsigned int p = ebuf[k];
        int pos = atomicAdd(&cur[(p >> 16) & 255], 1);
        esrc[pos] = (unsigned short)(p & 0xFFFFu);
    }
}

// ---------------- mean aggregation (CSR gather, bf16-hi plane) ----------------
// R5: max-residency gather, spill-proof. LDS-free, 1 node per 16-lane group,
// 6-deep load pipeline (16 acc + 24 in-flight + ~16 misc ~= 56 VGPR) under
// launch_bounds(256,8) -> 32 waves/CU (2x R2's fused kernel). 6-deep chosen
// over 8-deep to stay clear of the 64-VGPR spill cliff (R3 lesson).

__global__ __launch_bounds__(256, 8) void agg_kernel(
    const unsigned short* __restrict__ Hhi, const int* __restrict__ rowptr,
    const unsigned short* __restrict__ esrc,
    unsigned short* __restrict__ Ahi, int n) {
    int g = (blockIdx.x * blockDim.x + threadIdx.x) >> 4;
    int l16 = threadIdx.x & 15;
    if (g >= n) return;
    int beg = rowptr[g], end = rowptr[g + 1];
    const unsigned short* __restrict__ Hb = Hhi + l16 * 8;
    float a0[8] = {0,0,0,0,0,0,0,0}, a1[8] = {0,0,0,0,0,0,0,0};
    int k = beg;
    // 6-deep main loop: 6 independent 16B gathers in flight
    for (; k + 6 <= end; k += 6) {
        int e0 = esrc[k],     e1 = esrc[k + 1], e2 = esrc[k + 2];
        int e3 = esrc[k + 3], e4 = esrc[k + 4], e5 = esrc[k + 5];
        ushort8v v0 = *(const ushort8v*)(Hb + (size_t)e0 * 128);
        ushort8v v1 = *(const ushort8v*)(Hb + (size_t)e1 * 128);
        ushort8v v2 = *(const ushort8v*)(Hb + (size_t)e2 * 128);
        ushort8v v3 = *(const ushort8v*)(Hb + (size_t)e3 * 128);
        ushort8v v4 = *(const ushort8v*)(Hb + (size_t)e4 * 128);
        ushort8v v5 = *(const ushort8v*)(Hb + (size_t)e5 * 128);
#pragma unroll
        for (int j = 0; j < 8; ++j) {
            a0[j] += bf2f(v0[j]); a1[j] += bf2f(v1[j]);
            a0[j] += bf2f(v2[j]); a1[j] += bf2f(v3[j]);
            a0[j] += bf2f(v4[j]); a1[j] += bf2f(v5[j]);
        }
    }
    // pair drain
    for (; k + 2 <= end; k += 2) {
        int e0 = esrc[k], e1 = esrc[k + 1];
        ushort8v v0 = *(const ushort8v*)(Hb + (size_t)e0 * 128);
        ushort8v v1 = *(const ushort8v*)(Hb + (size_t)e1 * 128);
#pragma unroll
        for (int j = 0; j < 8; ++j) { a0[j] += bf2f(v0[j]); a1[j] += bf2f(v1[j]); }
    }
    if (k < end) {
        int e0 = esrc[k];
        ushort8v v0 = *(const ushort8v*)(Hb + (size_t)e0 * 128);
#pragma unroll
        for (int j = 0; j < 8; ++j) a0[j] += bf2f(v0[j]);
    }
    float inv = (end > beg) ? 1.0f / (float)(end - beg) : 0.0f;
    ushort8v mh;
#pragma unroll
    for (int j = 0; j < 8; ++j) mh[j] = f2bf((a0[j] + a1[j]) * inv);
    *(ushort8v*)(Ahi + (size_t)g * 128 + l16 * 8) = mh;
}

// ---------------- dual GEMM via MFMA (plane inputs, verbatim R0 staging) -----
// out = A1@W1 + A2@W2 + b (opt ReLU). A1 = agg (hi only, 2 MFMAs); A2 = self
// (hi+lo, 3 MFMAs). BM=32, 256 thr = 4 waves. In-place safe: block stages
// only its own 32 rows (all three planes) in LDS before writing them.

template <int DOUT, bool RELU, bool SPLIT_OUT>
__global__ __launch_bounds__(256, 4) void gemm_planes(
    const unsigned short* __restrict__ A1hi,
    const unsigned short* __restrict__ A2hi, const unsigned short* __restrict__ A2lo,
    const unsigned short* __restrict__ B1p, const unsigned short* __restrict__ B2p,
    const float* __restrict__ bias, float* __restrict__ outf,
    unsigned short* __restrict__ outhi, unsigned short* __restrict__ outlo, int M) {
    constexpr int K = 128, BM = 32, KS = 4, CT = DOUT / 16, CPW = CT / 4;
    constexpr int PITCH = K + 8;
    constexpr int HALF = CT * KS * 512;
    __shared__ unsigned short As[3][BM * PITCH];  // [agg-hi, self-hi, self-lo]

    const int tid = threadIdx.x;
    const int r0 = blockIdx.x * BM;

    const unsigned short* __restrict__ srcs[3] = {A1hi, A2hi, A2lo};
#pragma unroll
    for (int s = 0; s < 3; ++s) {
#pragma unroll
        for (int c = 0; c < 2; ++c) {
            int chunk = tid + c * 256;
            int row = chunk >> 4;
            int c8 = (chunk & 15) * 8;
            int grow = r0 + row; if (grow >= M) grow = M - 1;
            *(ushort8v*)(&As[s][row * PITCH + c8]) =
                *(const ushort8v*)(srcs[s] + (size_t)grow * K + c8);
        }
    }
    __syncthreads();

    const int wave = tid >> 6, lane = tid & 63;
    const int rl = lane & 15, quad = lane >> 4;

    f32x4 acc[2][CPW];
#pragma unroll
    for (int c = 0; c < CPW; ++c) {
        float bv = bias[(wave * CPW + c) * 16 + rl];
        acc[0][c] = (f32x4){bv, bv, bv, bv};
        acc[1][c] = acc[0][c];
    }

#pragma unroll
    for (int ks = 0; ks < KS; ++ks) {
        short8 a_ag[2], a_sh[2][2];
#pragma unroll
        for (int rt = 0; rt < 2; ++rt) {
            int off = (rt * 16 + rl) * PITCH + ks * 32 + quad * 8;
            a_ag[rt]    = *(const short8*)(&As[0][off]);
            a_sh[rt][0] = *(const short8*)(&As[1][off]);
            a_sh[rt][1] = *(const short8*)(&As[2][off]);
        }
        short8 b1[CPW][2], b2[CPW][2];
#pragma unroll
        for (int c = 0; c < CPW; ++c) {
            size_t boff = (((wave * CPW + c) * KS + ks) * 64 + lane) * 8;
#pragma unroll
            for (int p = 0; p < 2; ++p) {
                b1[c][p] = *(const short8*)(B1p + p * HALF + boff);
                b2[c][p] = *(const short8*)(B2p + p * HALF + boff);
            }
        }
#pragma unroll
        for (int rt = 0; rt < 2; ++rt)
#pragma unroll
            for (int c = 0; c < CPW; ++c) {
                acc[rt][c] = __builtin_amdgcn_mfma_f32_16x16x32_bf16(a_ag[rt],    b1[c][0], acc[rt][c], 0, 0, 0);
                acc[rt][c] = __builtin_amdgcn_mfma_f32_16x16x32_bf16(a_ag[rt],    b1[c][1], acc[rt][c], 0, 0, 0);
                acc[rt][c] = __builtin_amdgcn_mfma_f32_16x16x32_bf16(a_sh[rt][0], b2[c][0], acc[rt][c], 0, 0, 0);
                acc[rt][c] = __builtin_amdgcn_mfma_f32_16x16x32_bf16(a_sh[rt][0], b2[c][1], acc[rt][c], 0, 0, 0);
                acc[rt][c] = __builtin_amdgcn_mfma_f32_16x16x32_bf16(a_sh[rt][1], b2[c][0], acc[rt][c], 0, 0, 0);
            }
    }

    // ---- epilogue: C/D layout col=lane&15, row=quad*4+reg ----
#pragma unroll
    for (int rt = 0; rt < 2; ++rt)
#pragma unroll
        for (int c = 0; c < CPW; ++c) {
            int col = (wave * CPW + c) * 16 + rl;
            int rowb = r0 + rt * 16 + quad * 4;
#pragma unroll
            for (int r = 0; r < 4; ++r) {
                int rr = rowb + r;
                if (rr < M) {
                    float vv = acc[rt][c][r];
                    if (RELU) vv = fmaxf(vv, 0.f);
                    if (SPLIT_OUT) {
                        unsigned short h, l;
                        split_bf16(vv, h, l);
                        outhi[(size_t)rr * DOUT + col] = h;
                        outlo[(size_t)rr * DOUT + col] = l;
                    } else {
                        outf[(size_t)rr * DOUT + col] = vv;
                    }
                }
            }
        }
}

// ---------------- launch ----------------

extern "C" void kernel_launch(void* const* d_in, const int* in_sizes, int n_in,
                              void* d_out, int out_size, void* d_ws, size_t ws_size,
                              hipStream_t stream) {
    const float* x   = (const float*)d_in[0];
    const int* eidx  = (const int*)d_in[1];
    const int* src   = eidx;             // edge_index[0]
    const int* dst   = eidx + N_EDGES;   // edge_index[1]
    const float* Wl0 = (const float*)d_in[2];
    const float* b0  = (const float*)d_in[3];
    const float* Wr0 = (const float*)d_in[4];
    const float* Wl1 = (const float*)d_in[5];
    const float* b1  = (const float*)d_in[6];
    const float* Wr1 = (const float*)d_in[7];
    const float* Wl2 = (const float*)d_in[8];
    const float* b2  = (const float*)d_in[9];
    const float* Wr2 = (const float*)d_in[10];
    float* outp = (float*)d_out;

    // workspace (~41 MB, R0-verified layout)
    unsigned short* xhi  = (unsigned short*)d_ws;           // N*128 each
    unsigned short* xlo  = xhi + (size_t)N_NODES * 128;
    unsigned short* aghi = xlo + (size_t)N_NODES * 128;
    unsigned int* ebuf = (unsigned int*)aghi;               // ALIAS: consumed before agg writes
    int* rowptr    = (int*)(aghi + (size_t)N_NODES * 128);  // 50016
    int* blkhist   = rowptr + 50016;                        // 196*196 = 38416
    int* bucketBase= blkhist + 38416;                       // 256 (197 used)
    int* bucketCur = bucketBase + 256;                      // 256
    unsigned short* esrc  = (unsigned short*)(bucketCur + 256); // E ushort = 1.6MB
    unsigned short* packw = esrc + N_EDGES;                 // 163840 bf16 (16B-aligned)
    unsigned short* Wl0p = packw;
    unsigned short* Wr0p = packw + 32768;
    unsigned short* Wl1p = packw + 65536;
    unsigned short* Wr1p = packw + 98304;
    unsigned short* Wl2p = packw + 131072;
    unsigned short* Wr2p = packw + 147456;

    // --- prep (pack W + split x + per-block bucket hist; no atomics to global) ---
    prep_kernel<<<2079, 256, 0, stream>>>(Wl0, Wr0, Wl1, Wr1, Wl2, Wr2, packw,
                                          x, xhi, xlo, dst, blkhist);
    // --- bucket scan (1 block) -> bucketBase/bucketCur, rowptr[N]=E ---
    scan_sums_kernel<<<1, 256, 0, stream>>>(blkhist, bucketBase, bucketCur, rowptr);
    // --- partition edges into buckets (coalesced), then per-bucket CSR ---
    partition_kernel<<<(N_EDGES + 2047) / 2048, 256, 0, stream>>>(src, dst, bucketCur, ebuf, N_EDGES);
    fine_fill_kernel<<<NBUCK, 256, 0, stream>>>(ebuf, bucketBase, rowptr, esrc, N_NODES);

    const int aggGrid = (N_NODES * 16 + 255) / 256;   // 3125
    const int gemmGrid = (N_NODES + 31) / 32;         // 1563

    // layer 0: x -> x (in place, ReLU)
    agg_kernel<<<aggGrid, 256, 0, stream>>>(xhi, rowptr, esrc, aghi, N_NODES);
    gemm_planes<128, true, true><<<gemmGrid, 256, 0, stream>>>(
        aghi, xhi, xlo, Wl0p, Wr0p, b0, nullptr, xhi, xlo, N_NODES);
    // layer 1: x -> x (in place, ReLU)
    agg_kernel<<<aggGrid, 256, 0, stream>>>(xhi, rowptr, esrc, aghi, N_NODES);
    gemm_planes<128, true, true><<<gemmGrid, 256, 0, stream>>>(
        aghi, xhi, xlo, Wl1p, Wr1p, b1, nullptr, xhi, xlo, N_NODES);
    // layer 2: x -> out (f32, no ReLU, DOUT=64)
    agg_kernel<<<aggGrid, 256, 0, stream>>>(xhi, rowptr, esrc, aghi, N_NODES);
    gemm_planes<64, false, false><<<gemmGrid, 256, 0, stream>>>(
        aghi, xhi, xlo, Wl2p, Wr2p, b2, outp, nullptr, nullptr, N_NODES);
}